// Round 11
// baseline (269.710 us; speedup 1.0000x reference)
//
#include <hip/hip_runtime.h>
#include <math.h>
#include <stdint.h>

typedef __attribute__((ext_vector_type(8))) short short8;
typedef __attribute__((ext_vector_type(4))) float f32x4;

static __device__ __forceinline__ float lrelu(float x) { return x >= 0.f ? x : 0.2f * x; }

// round-to-nearest-even fp32 -> bf16 bits
static __device__ __forceinline__ uint32_t f2bf(float f) {
    uint32_t u = __float_as_uint(f);
    return (u + 0x7FFFu + ((u >> 16) & 1u)) >> 16;
}

// ---------------- count (XCD-partitioned) + wprep ----------------
// deg8[part][node], part=blockIdx&7: blocks round-robin to XCDs, so each
// counter line stays in ONE XCD's L2. rank[i] = within-partition rank.
// Blocks [eb, eb+128) additionally do W transpose->bf16.
__global__ __launch_bounds__(256) void count_wprep(const int* __restrict__ dst, int E, int N,
                                                   int* __restrict__ deg8,
                                                   int* __restrict__ rank, int eb,
                                                   const float* __restrict__ W1,
                                                   const float* __restrict__ W2,
                                                   uint16_t* __restrict__ wtb1,
                                                   uint16_t* __restrict__ wtb2) {
    if ((int)blockIdx.x < eb) {
        int i = blockIdx.x * 256 + threadIdx.x;
        int p = blockIdx.x & 7;
        if (i < E) rank[i] = atomicAdd(&deg8[p * N + dst[i]], 1);
    } else {
        int idx = (blockIdx.x - eb) * 256 + threadIdx.x;   // 0..32767
        const float* src = (idx < 16384) ? W1 : W2;
        uint16_t* dw = (idx < 16384) ? wtb1 : wtb2;
        int j = idx & 16383;
        dw[(j & 127) * 128 + (j >> 7)] = (uint16_t)f2bf(src[j]);  // [col][k]
    }
}

// ---------------- scan1: combine partitions + chunk-scan padded degrees ----
__global__ __launch_bounds__(256) void scan1(const int* __restrict__ deg8, int N, int ntot,
                                             int* __restrict__ deg,
                                             int* __restrict__ base8,
                                             int* __restrict__ rowptr,
                                             int* __restrict__ csum) {
    __shared__ int s[256];
    int t = threadIdx.x;
    int i = blockIdx.x * 256 + t;
    int v = 0;
    if (i < N) {
        int total = 0;
        #pragma unroll
        for (int p = 0; p < 8; ++p) {
            int c = deg8[p * N + i];
            base8[p * N + i] = total;      // prefix over partitions
            total += c;
        }
        deg[i] = total;
        v = (total + 31) & ~31;            // degree padded to mult of 32
    }
    s[t] = v;
    __syncthreads();
    #pragma unroll
    for (int off = 1; off < 256; off <<= 1) {
        int add = (t >= off) ? s[t - off] : 0;
        __syncthreads();
        s[t] += add;
        __syncthreads();
    }
    if (i < ntot) rowptr[i] = s[t] - v;    // exclusive within chunk
    if (t == 255) csum[blockIdx.x] = s[255];
}

__global__ __launch_bounds__(256) void scan2(const int* __restrict__ csum,
                                             int* __restrict__ coff, int nch) {
    __shared__ int s[256];
    int t = threadIdx.x;
    int v = (t < nch) ? csum[t] : 0;
    s[t] = v;
    __syncthreads();
    #pragma unroll
    for (int off = 1; off < 256; off <<= 1) {
        int add = (t >= off) ? s[t - off] : 0;
        __syncthreads();
        s[t] += add;
        __syncthreads();
    }
    coff[t] = s[t] - v;
}

__global__ __launch_bounds__(256) void scan3(int* __restrict__ rowptr,
                                             const int* __restrict__ coff, int ntot) {
    int i = blockIdx.x * 256 + threadIdx.x;
    if (i < ntot) rowptr[i] += coff[blockIdx.x];
}

// Merged fill: blocks [0,eb) scatter edges (atomic-free; same grid geometry
// as count_wprep so part=blockIdx&7 matches); blocks [eb,..) write sentinel
// + pads. colidx is uint16 (N+1 = 50001 < 65536).
__global__ __launch_bounds__(256) void fill_pad(const int* __restrict__ src,
                                                const int* __restrict__ dst,
                                                const int* __restrict__ rank, int E, int N,
                                                const int* __restrict__ rowptr,
                                                const int* __restrict__ deg,
                                                const int* __restrict__ base8,
                                                uint16_t* __restrict__ colidx,
                                                float* __restrict__ as_,
                                                uint32_t* __restrict__ hbf, int eb) {
    if ((int)blockIdx.x < eb) {
        int i = blockIdx.x * 256 + threadIdx.x;
        int p = blockIdx.x & 7;
        if (i < E) {
            int d = dst[i];
            colidx[rowptr[d] + base8[p * N + d] + rank[i]] = (uint16_t)src[i];
        }
    } else {
        int i = (blockIdx.x - eb) * 256 + threadIdx.x;
        if (i < 4) as_[N * 4 + i] = -1e30f;        // sentinel weight -> exactly 0
        if (i < 64) hbf[(size_t)N * 64 + i] = 0u;  // sentinel h row = 0
        if (i < N) {
            int b = rowptr[i] + deg[i];
            int e = rowptr[i + 1];
            for (int pp = b; pp < e; ++pp) colidx[pp] = (uint16_t)N;
        }
    }
}

// ---------------- MFMA GEMM + alpha ----------------
// h[r,128] = x[r,128] @ W[128,128] via mfma_f32_16x16x32_bf16 (round-9 design).
__global__ __launch_bounds__(256) void gemm_mfma(const float* __restrict__ x,
                                                 const uint16_t* __restrict__ wtb,
                                                 const float* __restrict__ a_src,
                                                 const float* __restrict__ a_dst,
                                                 uint32_t* __restrict__ hbf,
                                                 float* __restrict__ as_,
                                                 float* __restrict__ ad_,
                                                 int nrows) {
    __shared__ __align__(16) char lds[52224];      // xs 64*272 | wsT 128*272
    const int t = threadIdx.x;
    const int row0 = blockIdx.x * 64;

    {   // stage x -> bf16 LDS [64 rows][128 k], row stride 272B
        int r = t >> 2;
        int k16b = (t & 3) * 4;
        const float* xrow = x + (size_t)(row0 + r) * 128;
        bool ok = (row0 + r) < nrows;
        #pragma unroll
        for (int i = 0; i < 4; ++i) {
            int k16 = k16b + i;
            float4 va = make_float4(0.f, 0.f, 0.f, 0.f), vb = va;
            if (ok) {
                va = *(const float4*)(xrow + k16 * 8);
                vb = *(const float4*)(xrow + k16 * 8 + 4);
            }
            uint4 pk;
            pk.x = f2bf(va.x) | (f2bf(va.y) << 16);
            pk.y = f2bf(va.z) | (f2bf(va.w) << 16);
            pk.z = f2bf(vb.x) | (f2bf(vb.y) << 16);
            pk.w = f2bf(vb.z) | (f2bf(vb.w) << 16);
            *(uint4*)(lds + r * 272 + k16 * 16) = pk;
        }
    }
    {   // stage wtb (bf16 [col][k]) -> LDS, row stride 272B
        #pragma unroll
        for (int i = 0; i < 8; ++i) {
            int u = t * 8 + i;
            int col = u >> 4, k16 = u & 15;
            uint4 v = *(const uint4*)(wtb + col * 128 + k16 * 8);
            *(uint4*)(lds + 17408 + col * 272 + k16 * 16) = v;
        }
    }
    __syncthreads();

    const int w = t >> 6, lane = t & 63;
    const int wrow0 = w * 16;
    const int la = lane & 15, lb = lane >> 4;

    f32x4 acc[8];
    #pragma unroll
    for (int ct = 0; ct < 8; ++ct) acc[ct] = (f32x4){0.f, 0.f, 0.f, 0.f};

    const char* xsb = lds + (wrow0 + la) * 272;
    const char* wsb = lds + 17408;
    #pragma unroll
    for (int kc = 0; kc < 4; ++kc) {
        int k16 = kc * 4 + lb;
        short8 a = *(const short8*)(xsb + k16 * 16);
        #pragma unroll
        for (int ct = 0; ct < 8; ++ct) {
            int col = ct * 16 + la;
            short8 b = *(const short8*)(wsb + col * 272 + k16 * 16);
            acc[ct] = __builtin_amdgcn_mfma_f32_16x16x32_bf16(a, b, acc[ct], 0, 0, 0);
        }
    }
    __syncthreads();

    // D lane layout: col = la, row = lb*4 + r2 (within 16-row tile)
    float* scr = (float*)lds;                      // [64][132] f32
    #pragma unroll
    for (int ct = 0; ct < 8; ++ct)
        #pragma unroll
        for (int r2 = 0; r2 < 4; ++r2)
            scr[(wrow0 + lb * 4 + r2) * 132 + ct * 16 + la] = acc[ct][r2];
    __syncthreads();

    {   // final: thread -> (row, head q); pack hbf + alpha dots
        int row = t >> 2, q = t & 3;
        int grow = row0 + row;
        float v[32];
        #pragma unroll
        for (int m = 0; m < 8; ++m) {
            float4 f = *(const float4*)(scr + row * 132 + q * 32 + m * 4);
            v[m * 4 + 0] = f.x; v[m * 4 + 1] = f.y;
            v[m * 4 + 2] = f.z; v[m * 4 + 3] = f.w;
        }
        if (grow < nrows) {
            uint32_t* orow = hbf + (size_t)grow * 64 + q * 16;
            #pragma unroll
            for (int m2 = 0; m2 < 4; ++m2) {
                uint4 pk;
                pk.x = f2bf(v[m2 * 8 + 0]) | (f2bf(v[m2 * 8 + 1]) << 16);
                pk.y = f2bf(v[m2 * 8 + 2]) | (f2bf(v[m2 * 8 + 3]) << 16);
                pk.z = f2bf(v[m2 * 8 + 4]) | (f2bf(v[m2 * 8 + 5]) << 16);
                pk.w = f2bf(v[m2 * 8 + 6]) | (f2bf(v[m2 * 8 + 7]) << 16);
                *(uint4*)(orow + m2 * 4) = pk;
            }
            float ps = 0.f, pd = 0.f;
            const float* asp = a_src + q * 32;
            const float* adp = a_dst + q * 32;
            #pragma unroll
            for (int j = 0; j < 32; ++j) {
                ps = fmaf(v[j], asp[j], ps);
                pd = fmaf(v[j], adp[j], pd);
            }
            as_[grow * 4 + q] = ps;
            ad_[grow * 4 + q] = pd;
        }
    }
}

// ---------------- aggregation: one wave per dst node, bf16 h rows ----------------
// Rows padded to multiple of 32 -> one fully-pipelined 32-edge batch for most
// nodes (mean degree 17): 4 wave-uniform uint4 colidx loads + 32 independent
// hb gathers in flight before any consumption. Weight dedup: lane computes
// weights of edges (lane>>2) and (lane>>2)+16 for head lane&3; __shfl out.
__global__ __launch_bounds__(256) void aggregate(const uint32_t* __restrict__ hb,
                                                 const float* __restrict__ as_,
                                                 const float* __restrict__ ad_,
                                                 const int* __restrict__ rowptr,
                                                 const uint16_t* __restrict__ colidx,
                                                 const float* __restrict__ bias,
                                                 float* __restrict__ out, int n, int do_elu) {
    int node = blockIdx.x * 4 + (threadIdx.x >> 6);
    if (node >= n) return;
    int lane = threadIdx.x & 63;
    int hd = lane >> 4;
    int k = lane * 2;
    int ce = lane >> 2;          // edge-in-halfbatch this lane weighs (0..15)
    int ch = lane & 3;           // head this lane weighs
    float adn = ad_[node * 4 + hd];
    float adc = ad_[node * 4 + ch];
    float accx = 0.f, accy = 0.f, denom = 0.f;

    {   // self loop
        float wgt = __expf(lrelu(as_[node * 4 + hd] + adn));
        uint32_t u = hb[(size_t)node * 64 + lane];
        accx = fmaf(wgt, __uint_as_float(u << 16), accx);
        accy = fmaf(wgt, __uint_as_float(u & 0xFFFF0000u), accy);
        denom += wgt;
    }
    const int beg = rowptr[node], end = rowptr[node + 1];
    for (int j = beg; j < end; j += 32) {
        uint4 cA = *(const uint4*)(colidx + j);        // edges 0..7
        uint4 cB = *(const uint4*)(colidx + j + 8);    // edges 8..15
        uint4 cC = *(const uint4*)(colidx + j + 16);   // edges 16..23
        uint4 cD = *(const uint4*)(colidx + j + 24);   // edges 24..31
        int sE[32];
        sE[0]  = cA.x & 0xFFFF; sE[1]  = cA.x >> 16;
        sE[2]  = cA.y & 0xFFFF; sE[3]  = cA.y >> 16;
        sE[4]  = cA.z & 0xFFFF; sE[5]  = cA.z >> 16;
        sE[6]  = cA.w & 0xFFFF; sE[7]  = cA.w >> 16;
        sE[8]  = cB.x & 0xFFFF; sE[9]  = cB.x >> 16;
        sE[10] = cB.y & 0xFFFF; sE[11] = cB.y >> 16;
        sE[12] = cB.z & 0xFFFF; sE[13] = cB.z >> 16;
        sE[14] = cB.w & 0xFFFF; sE[15] = cB.w >> 16;
        sE[16] = cC.x & 0xFFFF; sE[17] = cC.x >> 16;
        sE[18] = cC.y & 0xFFFF; sE[19] = cC.y >> 16;
        sE[20] = cC.z & 0xFFFF; sE[21] = cC.z >> 16;
        sE[22] = cC.w & 0xFFFF; sE[23] = cC.w >> 16;
        sE[24] = cD.x & 0xFFFF; sE[25] = cD.x >> 16;
        sE[26] = cD.y & 0xFFFF; sE[27] = cD.y >> 16;
        sE[28] = cD.z & 0xFFFF; sE[29] = cD.z >> 16;
        sE[30] = cD.w & 0xFFFF; sE[31] = cD.w >> 16;
        int swA = colidx[j + ce];                      // per-lane scalar loads
        int swB = colidx[j + 16 + ce];
        float awA = as_[swA * 4 + ch];
        float awB = as_[swB * 4 + ch];
        uint32_t u[32];
        #pragma unroll
        for (int e = 0; e < 32; ++e) u[e] = hb[(size_t)sE[e] * 64 + lane];
        float wA = __expf(lrelu(awA + adc));
        float wB = __expf(lrelu(awB + adc));
        #pragma unroll
        for (int e = 0; e < 16; ++e) {
            float we = __shfl(wA, e * 4 + hd);
            accx = fmaf(we, __uint_as_float(u[e] << 16), accx);
            accy = fmaf(we, __uint_as_float(u[e] & 0xFFFF0000u), accy);
            denom += we;
        }
        #pragma unroll
        for (int e = 0; e < 16; ++e) {
            float we = __shfl(wB, e * 4 + hd);
            accx = fmaf(we, __uint_as_float(u[16 + e] << 16), accx);
            accy = fmaf(we, __uint_as_float(u[16 + e] & 0xFFFF0000u), accy);
            denom += we;
        }
    }
    float inv = 1.f / (denom + 1e-16f);
    float o0 = fmaf(accx, inv, bias[k]);
    float o1 = fmaf(accy, inv, bias[k + 1]);
    if (do_elu) {
        o0 = o0 > 0.f ? o0 : (__expf(o0) - 1.f);
        o1 = o1 > 0.f ? o1 : (__expf(o1) - 1.f);
    }
    *(float2*)&out[(size_t)node * 128 + k] = make_float2(o0, o1);
}

extern "C" void kernel_launch(void* const* d_in, const int* in_sizes, int n_in,
                              void* d_out, int out_size, void* d_ws, size_t ws_size,
                              hipStream_t stream) {
    const float* x   = (const float*)d_in[0];
    const int*   ei  = (const int*)d_in[1];
    const float* W1  = (const float*)d_in[2];
    const float* a1s = (const float*)d_in[3];
    const float* a1d = (const float*)d_in[4];
    const float* b1  = (const float*)d_in[5];
    const float* W2  = (const float*)d_in[6];
    const float* a2s = (const float*)d_in[7];
    const float* a2d = (const float*)d_in[8];
    const float* b2  = (const float*)d_in[9];
    float* out = (float*)d_out;

    const int N = in_sizes[0] / 128;   // 50000; N+1 fits uint16 (colidx)
    const int E = in_sizes[1] / 2;
    const int* esrc = ei;
    const int* edst = ei + E;

    char* w = (char*)d_ws;
    uint32_t* hbf  = (uint32_t*)w; w += (size_t)(N + 1) * 64 * 4;  // +sentinel row
    float*    as_  = (float*)w;    w += (size_t)(N + 1) * 4 * 4;   // +sentinel
    float*    ad_  = (float*)w;    w += (size_t)(N + 1) * 4 * 4;
    int* deg    = (int*)w;   w += (size_t)N * 4;
    int* rowptr = (int*)w;   w += (size_t)(N + 1) * 4;
    int* rank   = (int*)w;   w += (size_t)E * 4;
    int* deg8   = (int*)w;   w += (size_t)8 * N * 4;               // per-XCD counters
    int* base8  = (int*)w;   w += (size_t)8 * N * 4;               // partition prefixes
    int* csum   = (int*)w;   w += 256 * 4;
    int* coff   = (int*)w;   w += 256 * 4;
    uint16_t* wtb1 = (uint16_t*)w; w += 16384 * 2;                 // bf16 W1^T [col][k]
    uint16_t* wtb2 = (uint16_t*)w; w += 16384 * 2;
    w = (char*)(((uintptr_t)w + 31) & ~(uintptr_t)31);             // 32B align
    uint16_t* colidx = (uint16_t*)w; w += ((size_t)E + 32ull * N) * 2;  // padded CSR, u16
    float* out1 = out;   // layer-1 output in d_out; consumed by layer-2 gemm
                         // before the final aggregate overwrites d_out

    hipMemsetAsync(deg8, 0, (size_t)8 * N * 4, stream);

    const int eb = (E + 255) / 256;
    const int ntot = N + 1;
    const int nch = (ntot + 255) / 256;
    const int gb = (N + 63) / 64;
    const int nb = (N + 3) / 4;
    const int pb = (N + 255) / 256;

    count_wprep<<<eb + 128, 256, 0, stream>>>(edst, E, N, deg8, rank, eb,
                                              W1, W2, wtb1, wtb2);
    scan1<<<nch, 256, 0, stream>>>(deg8, N, ntot, deg, base8, rowptr, csum);
    scan2<<<1, 256, 0, stream>>>(csum, coff, nch);
    scan3<<<nch, 256, 0, stream>>>(rowptr, coff, ntot);
    fill_pad<<<eb + pb, 256, 0, stream>>>(esrc, edst, rank, E, N, rowptr, deg,
                                          base8, colidx, as_, hbf, eb);

    // layer 1
    gemm_mfma<<<gb, 256, 0, stream>>>(x, wtb1, a1s, a1d, hbf, as_, ad_, N);
    aggregate<<<nb, 256, 0, stream>>>(hbf, as_, ad_, rowptr, colidx, b1, out1, N, 1);

    // layer 2
    gemm_mfma<<<gb, 256, 0, stream>>>(out1, wtb2, a2s, a2d, hbf, as_, ad_, N);
    aggregate<<<nb, 256, 0, stream>>>(hbf, as_, ad_, rowptr, colidx, b2, out, N, 0);
}

// Round 12
// 265.219 us; speedup vs baseline: 1.0169x; 1.0169x over previous
//
#include <hip/hip_runtime.h>
#include <math.h>
#include <stdint.h>

typedef __attribute__((ext_vector_type(8))) short short8;
typedef __attribute__((ext_vector_type(4))) float f32x4;

static __device__ __forceinline__ float lrelu(float x) { return x >= 0.f ? x : 0.2f * x; }

// round-to-nearest-even fp32 -> bf16 bits
static __device__ __forceinline__ uint32_t f2bf(float f) {
    uint32_t u = __float_as_uint(f);
    return (u + 0x7FFFu + ((u >> 16) & 1u)) >> 16;
}
static __device__ __forceinline__ float bflo(uint32_t u) { return __uint_as_float(u << 16); }
static __device__ __forceinline__ float bfhi(uint32_t u) { return __uint_as_float(u & 0xFFFF0000u); }

// ---------------- count (XCD-partitioned) + wprep ----------------
__global__ __launch_bounds__(256) void count_wprep(const int* __restrict__ dst, int E, int N,
                                                   int* __restrict__ deg8,
                                                   int* __restrict__ rank, int eb,
                                                   const float* __restrict__ W1,
                                                   const float* __restrict__ W2,
                                                   uint16_t* __restrict__ wtb1,
                                                   uint16_t* __restrict__ wtb2) {
    if ((int)blockIdx.x < eb) {
        int i = blockIdx.x * 256 + threadIdx.x;
        int p = blockIdx.x & 7;
        if (i < E) rank[i] = atomicAdd(&deg8[p * N + dst[i]], 1);
    } else {
        int idx = (blockIdx.x - eb) * 256 + threadIdx.x;   // 0..32767
        const float* src = (idx < 16384) ? W1 : W2;
        uint16_t* dw = (idx < 16384) ? wtb1 : wtb2;
        int j = idx & 16383;
        dw[(j & 127) * 128 + (j >> 7)] = (uint16_t)f2bf(src[j]);  // [col][k]
    }
}

// ---------------- scan1: combine partitions + chunk-scan padded degrees ----
__global__ __launch_bounds__(256) void scan1(const int* __restrict__ deg8, int N, int ntot,
                                             int* __restrict__ deg,
                                             int* __restrict__ base8,
                                             int* __restrict__ rowptr,
                                             int* __restrict__ csum) {
    __shared__ int s[256];
    int t = threadIdx.x;
    int i = blockIdx.x * 256 + t;
    int v = 0;
    if (i < N) {
        int total = 0;
        #pragma unroll
        for (int p = 0; p < 8; ++p) {
            int c = deg8[p * N + i];
            base8[p * N + i] = total;      // prefix over partitions
            total += c;
        }
        deg[i] = total;
        v = (total + 15) & ~15;            // degree padded to mult of 16 (reverted)
    }
    s[t] = v;
    __syncthreads();
    #pragma unroll
    for (int off = 1; off < 256; off <<= 1) {
        int add = (t >= off) ? s[t - off] : 0;
        __syncthreads();
        s[t] += add;
        __syncthreads();
    }
    if (i < ntot) rowptr[i] = s[t] - v;    // exclusive within chunk
    if (t == 255) csum[blockIdx.x] = s[255];
}

__global__ __launch_bounds__(256) void scan2(const int* __restrict__ csum,
                                             int* __restrict__ coff, int nch) {
    __shared__ int s[256];
    int t = threadIdx.x;
    int v = (t < nch) ? csum[t] : 0;
    s[t] = v;
    __syncthreads();
    #pragma unroll
    for (int off = 1; off < 256; off <<= 1) {
        int add = (t >= off) ? s[t - off] : 0;
        __syncthreads();
        s[t] += add;
        __syncthreads();
    }
    coff[t] = s[t] - v;
}

__global__ __launch_bounds__(256) void scan3(int* __restrict__ rowptr,
                                             const int* __restrict__ coff, int ntot) {
    int i = blockIdx.x * 256 + threadIdx.x;
    if (i < ntot) rowptr[i] += coff[blockIdx.x];
}

// Merged fill: blocks [0,eb) scatter edges; blocks [eb,..) sentinel + pads.
__global__ __launch_bounds__(256) void fill_pad(const int* __restrict__ src,
                                                const int* __restrict__ dst,
                                                const int* __restrict__ rank, int E, int N,
                                                const int* __restrict__ rowptr,
                                                const int* __restrict__ deg,
                                                const int* __restrict__ base8,
                                                uint16_t* __restrict__ colidx,
                                                float* __restrict__ as_,
                                                uint32_t* __restrict__ hbf, int eb) {
    if ((int)blockIdx.x < eb) {
        int i = blockIdx.x * 256 + threadIdx.x;
        int p = blockIdx.x & 7;
        if (i < E) {
            int d = dst[i];
            colidx[rowptr[d] + base8[p * N + d] + rank[i]] = (uint16_t)src[i];
        }
    } else {
        int i = (blockIdx.x - eb) * 256 + threadIdx.x;
        if (i < 4) as_[N * 4 + i] = -1e30f;        // sentinel weight -> exactly 0
        if (i < 64) hbf[(size_t)N * 64 + i] = 0u;  // sentinel h row = 0
        if (i < N) {
            int b = rowptr[i] + deg[i];
            int e = rowptr[i + 1];
            for (int pp = b; pp < e; ++pp) colidx[pp] = (uint16_t)N;
        }
    }
}

// ---------------- MFMA GEMM + alpha ----------------
__global__ __launch_bounds__(256) void gemm_mfma(const float* __restrict__ x,
                                                 const uint16_t* __restrict__ wtb,
                                                 const float* __restrict__ a_src,
                                                 const float* __restrict__ a_dst,
                                                 uint32_t* __restrict__ hbf,
                                                 float* __restrict__ as_,
                                                 float* __restrict__ ad_,
                                                 int nrows) {
    __shared__ __align__(16) char lds[52224];      // xs 64*272 | wsT 128*272
    const int t = threadIdx.x;
    const int row0 = blockIdx.x * 64;

    {   // stage x -> bf16 LDS [64 rows][128 k], row stride 272B
        int r = t >> 2;
        int k16b = (t & 3) * 4;
        const float* xrow = x + (size_t)(row0 + r) * 128;
        bool ok = (row0 + r) < nrows;
        #pragma unroll
        for (int i = 0; i < 4; ++i) {
            int k16 = k16b + i;
            float4 va = make_float4(0.f, 0.f, 0.f, 0.f), vb = va;
            if (ok) {
                va = *(const float4*)(xrow + k16 * 8);
                vb = *(const float4*)(xrow + k16 * 8 + 4);
            }
            uint4 pk;
            pk.x = f2bf(va.x) | (f2bf(va.y) << 16);
            pk.y = f2bf(va.z) | (f2bf(va.w) << 16);
            pk.z = f2bf(vb.x) | (f2bf(vb.y) << 16);
            pk.w = f2bf(vb.z) | (f2bf(vb.w) << 16);
            *(uint4*)(lds + r * 272 + k16 * 16) = pk;
        }
    }
    {   // stage wtb (bf16 [col][k]) -> LDS, row stride 272B
        #pragma unroll
        for (int i = 0; i < 8; ++i) {
            int u = t * 8 + i;
            int col = u >> 4, k16 = u & 15;
            uint4 v = *(const uint4*)(wtb + col * 128 + k16 * 8);
            *(uint4*)(lds + 17408 + col * 272 + k16 * 16) = v;
        }
    }
    __syncthreads();

    const int w = t >> 6, lane = t & 63;
    const int wrow0 = w * 16;
    const int la = lane & 15, lb = lane >> 4;

    f32x4 acc[8];
    #pragma unroll
    for (int ct = 0; ct < 8; ++ct) acc[ct] = (f32x4){0.f, 0.f, 0.f, 0.f};

    const char* xsb = lds + (wrow0 + la) * 272;
    const char* wsb = lds + 17408;
    #pragma unroll
    for (int kc = 0; kc < 4; ++kc) {
        int k16 = kc * 4 + lb;
        short8 a = *(const short8*)(xsb + k16 * 16);
        #pragma unroll
        for (int ct = 0; ct < 8; ++ct) {
            int col = ct * 16 + la;
            short8 b = *(const short8*)(wsb + col * 272 + k16 * 16);
            acc[ct] = __builtin_amdgcn_mfma_f32_16x16x32_bf16(a, b, acc[ct], 0, 0, 0);
        }
    }
    __syncthreads();

    // D lane layout: col = la, row = lb*4 + r2 (within 16-row tile)
    float* scr = (float*)lds;                      // [64][132] f32
    #pragma unroll
    for (int ct = 0; ct < 8; ++ct)
        #pragma unroll
        for (int r2 = 0; r2 < 4; ++r2)
            scr[(wrow0 + lb * 4 + r2) * 132 + ct * 16 + la] = acc[ct][r2];
    __syncthreads();

    {   // final: thread -> (row, head q); pack hbf + alpha dots
        int row = t >> 2, q = t & 3;
        int grow = row0 + row;
        float v[32];
        #pragma unroll
        for (int m = 0; m < 8; ++m) {
            float4 f = *(const float4*)(scr + row * 132 + q * 32 + m * 4);
            v[m * 4 + 0] = f.x; v[m * 4 + 1] = f.y;
            v[m * 4 + 2] = f.z; v[m * 4 + 3] = f.w;
        }
        if (grow < nrows) {
            uint32_t* orow = hbf + (size_t)grow * 64 + q * 16;
            #pragma unroll
            for (int m2 = 0; m2 < 4; ++m2) {
                uint4 pk;
                pk.x = f2bf(v[m2 * 8 + 0]) | (f2bf(v[m2 * 8 + 1]) << 16);
                pk.y = f2bf(v[m2 * 8 + 2]) | (f2bf(v[m2 * 8 + 3]) << 16);
                pk.z = f2bf(v[m2 * 8 + 4]) | (f2bf(v[m2 * 8 + 5]) << 16);
                pk.w = f2bf(v[m2 * 8 + 6]) | (f2bf(v[m2 * 8 + 7]) << 16);
                *(uint4*)(orow + m2 * 4) = pk;
            }
            float ps = 0.f, pd = 0.f;
            const float* asp = a_src + q * 32;
            const float* adp = a_dst + q * 32;
            #pragma unroll
            for (int j = 0; j < 32; ++j) {
                ps = fmaf(v[j], asp[j], ps);
                pd = fmaf(v[j], adp[j], pd);
            }
            as_[grow * 4 + q] = ps;
            ad_[grow * 4 + q] = pd;
        }
    }
}

// ---------------- aggregation: quad-gather, one wave per dst node ----------------
// Row reads as dwordx4: 16 lanes cover one 256B hb row, so ONE gather
// instruction serves 4 edges (lane-group lane>>4 owns edge subset
// {g*4+grp}).  Lane owns cols (lane&15)*8..+7 (single head).  Per 16-edge
// batch: 4 gathers + 4 weight-shfl instead of 16 gathers + 16 shfl + 32-inst
// decode.  Cross-group combine via shfl_xor(16/32) once per node at the end.
__global__ __launch_bounds__(256) void aggregate(const uint32_t* __restrict__ hb,
                                                 const float* __restrict__ as_,
                                                 const float* __restrict__ ad_,
                                                 const int* __restrict__ rowptr,
                                                 const uint16_t* __restrict__ colidx,
                                                 const float* __restrict__ bias,
                                                 float* __restrict__ out, int n, int do_elu) {
    int node = blockIdx.x * 4 + (threadIdx.x >> 6);
    if (node >= n) return;
    int L = threadIdx.x & 63;
    int g16 = L & 15;            // col block: cols g16*8 .. g16*8+7
    int grp = L >> 4;            // lane group = edge subset {g*4+grp}
    int hd = g16 >> 2;           // head of this lane's cols
    int cw_e = L >> 2;           // weight-duty edge (0..15)
    int cw_h = L & 3;            // weight-duty head
    float adn = ad_[node * 4 + hd];
    float adc = ad_[node * 4 + cw_h];

    float acc[8];
    #pragma unroll
    for (int i = 0; i < 8; ++i) acc[i] = 0.f;
    float den = 0.f;

    const int beg = rowptr[node], end = rowptr[node + 1];
    for (int j = beg; j < end; j += 16) {
        // weight duty: this lane computes w(edge cw_e, head cw_h)
        int sw = colidx[j + cw_e];
        float w = __expf(lrelu(as_[sw * 4 + cw_h] + adc));
        // quad gathers: edge e = g*4+grp, 16B of its row at col-block g16
        uint4 u0, u1, u2, u3;
        {
            int s0 = colidx[j + grp];
            int s1 = colidx[j + 4 + grp];
            int s2 = colidx[j + 8 + grp];
            int s3 = colidx[j + 12 + grp];
            u0 = *(const uint4*)(hb + (size_t)s0 * 64 + g16 * 4);
            u1 = *(const uint4*)(hb + (size_t)s1 * 64 + g16 * 4);
            u2 = *(const uint4*)(hb + (size_t)s2 * 64 + g16 * 4);
            u3 = *(const uint4*)(hb + (size_t)s3 * 64 + g16 * 4);
        }
        float w0 = __shfl(w, ((0 * 4 + grp) << 2) | hd);
        float w1 = __shfl(w, ((1 * 4 + grp) << 2) | hd);
        float w2 = __shfl(w, ((2 * 4 + grp) << 2) | hd);
        float w3 = __shfl(w, ((3 * 4 + grp) << 2) | hd);
        acc[0] = fmaf(w0, bflo(u0.x), acc[0]); acc[1] = fmaf(w0, bfhi(u0.x), acc[1]);
        acc[2] = fmaf(w0, bflo(u0.y), acc[2]); acc[3] = fmaf(w0, bfhi(u0.y), acc[3]);
        acc[4] = fmaf(w0, bflo(u0.z), acc[4]); acc[5] = fmaf(w0, bfhi(u0.z), acc[5]);
        acc[6] = fmaf(w0, bflo(u0.w), acc[6]); acc[7] = fmaf(w0, bfhi(u0.w), acc[7]);
        acc[0] = fmaf(w1, bflo(u1.x), acc[0]); acc[1] = fmaf(w1, bfhi(u1.x), acc[1]);
        acc[2] = fmaf(w1, bflo(u1.y), acc[2]); acc[3] = fmaf(w1, bfhi(u1.y), acc[3]);
        acc[4] = fmaf(w1, bflo(u1.z), acc[4]); acc[5] = fmaf(w1, bfhi(u1.z), acc[5]);
        acc[6] = fmaf(w1, bflo(u1.w), acc[6]); acc[7] = fmaf(w1, bfhi(u1.w), acc[7]);
        acc[0] = fmaf(w2, bflo(u2.x), acc[0]); acc[1] = fmaf(w2, bfhi(u2.x), acc[1]);
        acc[2] = fmaf(w2, bflo(u2.y), acc[2]); acc[3] = fmaf(w2, bfhi(u2.y), acc[3]);
        acc[4] = fmaf(w2, bflo(u2.z), acc[4]); acc[5] = fmaf(w2, bfhi(u2.z), acc[5]);
        acc[6] = fmaf(w2, bflo(u2.w), acc[6]); acc[7] = fmaf(w2, bfhi(u2.w), acc[7]);
        acc[0] = fmaf(w3, bflo(u3.x), acc[0]); acc[1] = fmaf(w3, bfhi(u3.x), acc[1]);
        acc[2] = fmaf(w3, bflo(u3.y), acc[2]); acc[3] = fmaf(w3, bfhi(u3.y), acc[3]);
        acc[4] = fmaf(w3, bflo(u3.z), acc[4]); acc[5] = fmaf(w3, bfhi(u3.z), acc[5]);
        acc[6] = fmaf(w3, bflo(u3.w), acc[6]); acc[7] = fmaf(w3, bfhi(u3.w), acc[7]);
        den += (w0 + w1) + (w2 + w3);
    }

    // combine the 4 lane-group partials (lanes L, L^16, L^32, L^48 share g16)
    #pragma unroll
    for (int i = 0; i < 8; ++i) {
        acc[i] += __shfl_xor(acc[i], 16);
        acc[i] += __shfl_xor(acc[i], 32);
    }
    den += __shfl_xor(den, 16);
    den += __shfl_xor(den, 32);

    // self loop (added once, after the reduction)
    {
        float ws = __expf(lrelu(as_[node * 4 + hd] + adn));
        uint4 us = *(const uint4*)(hb + (size_t)node * 64 + g16 * 4);
        acc[0] = fmaf(ws, bflo(us.x), acc[0]); acc[1] = fmaf(ws, bfhi(us.x), acc[1]);
        acc[2] = fmaf(ws, bflo(us.y), acc[2]); acc[3] = fmaf(ws, bfhi(us.y), acc[3]);
        acc[4] = fmaf(ws, bflo(us.z), acc[4]); acc[5] = fmaf(ws, bfhi(us.z), acc[5]);
        acc[6] = fmaf(ws, bflo(us.w), acc[6]); acc[7] = fmaf(ws, bfhi(us.w), acc[7]);
        den += ws;
    }

    if (grp == 0) {   // groups hold identical sums after xor-reduce; one writes
        float inv = 1.f / (den + 1e-16f);
        float4 b0 = *(const float4*)(bias + g16 * 8);
        float4 b1 = *(const float4*)(bias + g16 * 8 + 4);
        float o[8];
        o[0] = fmaf(acc[0], inv, b0.x); o[1] = fmaf(acc[1], inv, b0.y);
        o[2] = fmaf(acc[2], inv, b0.z); o[3] = fmaf(acc[3], inv, b0.w);
        o[4] = fmaf(acc[4], inv, b1.x); o[5] = fmaf(acc[5], inv, b1.y);
        o[6] = fmaf(acc[6], inv, b1.z); o[7] = fmaf(acc[7], inv, b1.w);
        if (do_elu) {
            #pragma unroll
            for (int i = 0; i < 8; ++i)
                o[i] = o[i] > 0.f ? o[i] : (__expf(o[i]) - 1.f);
        }
        float* orow = out + (size_t)node * 128 + g16 * 8;
        *(float4*)orow       = make_float4(o[0], o[1], o[2], o[3]);
        *(float4*)(orow + 4) = make_float4(o[4], o[5], o[6], o[7]);
    }
}

extern "C" void kernel_launch(void* const* d_in, const int* in_sizes, int n_in,
                              void* d_out, int out_size, void* d_ws, size_t ws_size,
                              hipStream_t stream) {
    const float* x   = (const float*)d_in[0];
    const int*   ei  = (const int*)d_in[1];
    const float* W1  = (const float*)d_in[2];
    const float* a1s = (const float*)d_in[3];
    const float* a1d = (const float*)d_in[4];
    const float* b1  = (const float*)d_in[5];
    const float* W2  = (const float*)d_in[6];
    const float* a2s = (const float*)d_in[7];
    const float* a2d = (const float*)d_in[8];
    const float* b2  = (const float*)d_in[9];
    float* out = (float*)d_out;

    const int N = in_sizes[0] / 128;   // 50000; N+1 fits uint16 (colidx)
    const int E = in_sizes[1] / 2;
    const int* esrc = ei;
    const int* edst = ei + E;

    char* w = (char*)d_ws;
    uint32_t* hbf  = (uint32_t*)w; w += (size_t)(N + 1) * 64 * 4;  // +sentinel row
    float*    as_  = (float*)w;    w += (size_t)(N + 1) * 4 * 4;   // +sentinel
    float*    ad_  = (float*)w;    w += (size_t)(N + 1) * 4 * 4;
    int* deg    = (int*)w;   w += (size_t)N * 4;
    int* rowptr = (int*)w;   w += (size_t)(N + 1) * 4;
    int* rank   = (int*)w;   w += (size_t)E * 4;
    int* deg8   = (int*)w;   w += (size_t)8 * N * 4;               // per-XCD counters
    int* base8  = (int*)w;   w += (size_t)8 * N * 4;               // partition prefixes
    int* csum   = (int*)w;   w += 256 * 4;
    int* coff   = (int*)w;   w += 256 * 4;
    uint16_t* wtb1 = (uint16_t*)w; w += 16384 * 2;                 // bf16 W1^T [col][k]
    uint16_t* wtb2 = (uint16_t*)w; w += 16384 * 2;
    w = (char*)(((uintptr_t)w + 31) & ~(uintptr_t)31);             // 32B align
    uint16_t* colidx = (uint16_t*)w; w += ((size_t)E + 16ull * N) * 2;  // padded CSR, u16
    float* out1 = out;   // layer-1 output in d_out; consumed by layer-2 gemm
                         // before the final aggregate overwrites d_out

    hipMemsetAsync(deg8, 0, (size_t)8 * N * 4, stream);

    const int eb = (E + 255) / 256;
    const int ntot = N + 1;
    const int nch = (ntot + 255) / 256;
    const int gb = (N + 63) / 64;
    const int nb = (N + 3) / 4;
    const int pb = (N + 255) / 256;

    count_wprep<<<eb + 128, 256, 0, stream>>>(edst, E, N, deg8, rank, eb,
                                              W1, W2, wtb1, wtb2);
    scan1<<<nch, 256, 0, stream>>>(deg8, N, ntot, deg, base8, rowptr, csum);
    scan2<<<1, 256, 0, stream>>>(csum, coff, nch);
    scan3<<<nch, 256, 0, stream>>>(rowptr, coff, ntot);
    fill_pad<<<eb + pb, 256, 0, stream>>>(esrc, edst, rank, E, N, rowptr, deg,
                                          base8, colidx, as_, hbf, eb);

    // layer 1
    gemm_mfma<<<gb, 256, 0, stream>>>(x, wtb1, a1s, a1d, hbf, as_, ad_, N);
    aggregate<<<nb, 256, 0, stream>>>(hbf, as_, ad_, rowptr, colidx, b1, out1, N, 1);

    // layer 2
    gemm_mfma<<<gb, 256, 0, stream>>>(out1, wtb2, a2s, a2d, hbf, as_, ad_, N);
    aggregate<<<nb, 256, 0, stream>>>(hbf, as_, ad_, rowptr, colidx, b2, out, N, 0);
}